// Round 8
// baseline (836.102 us; speedup 1.0000x reference)
//
#include <hip/hip_runtime.h>
#include <hip/hip_bf16.h>
#include <cstdint>

#define BN_EPS 1e-5f
#define CSR_SHIFT 7
#define NBMAX 512

typedef __attribute__((ext_vector_type(8))) short short8;
typedef __attribute__((ext_vector_type(8))) __bf16 bf16x8;
typedef __attribute__((ext_vector_type(4))) float f32x4;

__device__ inline short f2bf(float f) {
    union { float f; unsigned u; } v; v.f = f;
    unsigned r = v.u + 0x7fffu + ((v.u >> 16) & 1u); // RNE
    return (short)(r >> 16);
}
__device__ inline float bf2f(short h) {
    union { unsigned u; float f; } v;
    v.u = ((unsigned)(unsigned short)h) << 16;
    return v.f;
}
__device__ inline unsigned asu(float f) { union { float f; unsigned u; } v; v.f = f; return v.u; }
__device__ inline float asf(unsigned u) { union { unsigned u; float f; } v; v.u = u; return v.f; }

// ---------------- fused setup: zero stats/bucketCnt, h0->bf16, weight split ----------------

__global__ __launch_bounds__(256) void setup_kernel(
    const float* __restrict__ h, unsigned short* __restrict__ hb, int total4,
    const float* __restrict__ W1, const float* __restrict__ W2,
    short* __restrict__ WtHi, short* __restrict__ WtLo,
    float* __restrict__ stats, int nstats, int* __restrict__ bcnt, int nb) {
    int i = blockIdx.x * 256 + threadIdx.x;
    if (i < nstats) stats[i] = 0.f;
    if (i < nb) bcnt[i] = 0;
    if (i < 10 * 128 * 128) {
        int mat = i >> 14, n = (i >> 7) & 127, k = i & 127;
        const float* W = (mat < 5) ? (W1 + mat * 16384) : (W2 + (mat - 5) * 16384);
        float w = W[k * 128 + n];
        short hi = f2bf(w);
        WtHi[i] = hi;
        WtLo[i] = f2bf(w - bf2f(hi));
    }
    if (i < total4) {
        float4 v = ((const float4*)h)[i];
        ushort4 o;
        o.x = (unsigned short)f2bf(v.x);
        o.y = (unsigned short)f2bf(v.y);
        o.z = (unsigned short)f2bf(v.z);
        o.w = (unsigned short)f2bf(v.w);
        ((ushort4*)hb)[i] = o;
    }
}

// ---- bucketed CSR build: bucket = dst >> 7 (128 nodes/bucket) ----

__global__ __launch_bounds__(256) void bcount_kernel(const int* __restrict__ dst,
                                                     int* __restrict__ bucketCnt,
                                                     int E, int nb, int chunk) {
    __shared__ int hist[NBMAX];
    int t = threadIdx.x;
    for (int i = t; i < nb; i += 256) hist[i] = 0;
    __syncthreads();
    int s = blockIdx.x * chunk, e = s + chunk; if (e > E) e = E;
    for (int i = s + t; i < e; i += 256) atomicAdd(&hist[dst[i] >> CSR_SHIFT], 1);
    __syncthreads();
    for (int i = t; i < nb; i += 256) if (hist[i]) atomicAdd(&bucketCnt[i], hist[i]);
}

__global__ __launch_bounds__(512) void bscan_kernel(const int* __restrict__ bucketCnt,
                                                    int* __restrict__ bucketBase,
                                                    int* __restrict__ bucketCursor,
                                                    int* __restrict__ rowptr,
                                                    int nb, int N, int E) {
    __shared__ int ps[NBMAX];
    int t = threadIdx.x;
    int v = (t < nb) ? bucketCnt[t] : 0;
    ps[t] = v;
    __syncthreads();
#pragma unroll
    for (int off = 1; off < NBMAX; off <<= 1) {
        int u = 0;
        if (t >= off) u = ps[t - off];
        __syncthreads();
        ps[t] += u;
        __syncthreads();
    }
    if (t < nb) {
        int b = ps[t] - v; // exclusive
        bucketBase[t] = b;
        bucketCursor[t] = b;
    }
    if (t == 0) { bucketBase[nb] = E; rowptr[N] = E; }
}

__global__ __launch_bounds__(256) void bscatter_kernel(const int* __restrict__ src,
                                                       const int* __restrict__ dst,
                                                       int* __restrict__ bucketCursor,
                                                       uint2* __restrict__ pairs,
                                                       int E, int nb, int chunk) {
    __shared__ int cnt[NBMAX];
    __shared__ int base[NBMAX];
    int t = threadIdx.x;
    for (int i = t; i < nb; i += 256) cnt[i] = 0;
    __syncthreads();
    int s = blockIdx.x * chunk, e = s + chunk; if (e > E) e = E;
    for (int i = s + t; i < e; i += 256) atomicAdd(&cnt[dst[i] >> CSR_SHIFT], 1);
    __syncthreads();
    for (int i = t; i < nb; i += 256) {
        int c = cnt[i];
        base[i] = c ? atomicAdd(&bucketCursor[i], c) : 0;
    }
    __syncthreads();
    for (int i = t; i < nb; i += 256) cnt[i] = 0;
    __syncthreads();
    for (int i = s + t; i < e; i += 256) {
        int d = dst[i];
        int b = d >> CSR_SHIFT;
        int slot = atomicAdd(&cnt[b], 1);
        pairs[base[b] + slot] = make_uint2((unsigned)src[i], (unsigned)d);
    }
}

__global__ __launch_bounds__(256) void bbuild_kernel(const uint2* __restrict__ pairs,
                                                     const int* __restrict__ bucketBase,
                                                     int* __restrict__ rowptr,
                                                     int* __restrict__ colidx, int N) {
    __shared__ int cnt[128];
    int b = blockIdx.x, t = threadIdx.x;
    int lo = bucketBase[b], hi = bucketBase[b + 1];
    if (t < 128) cnt[t] = 0;
    __syncthreads();
    for (int e = lo + t; e < hi; e += 256) atomicAdd(&cnt[pairs[e].y & 127], 1);
    __syncthreads();
    int orig = (t < 128) ? cnt[t] : 0;
#pragma unroll
    for (int o = 1; o < 128; o <<= 1) {
        int u = 0;
        if (t < 128 && t >= o) u = cnt[t - o];
        __syncthreads();
        if (t < 128) cnt[t] += u;
        __syncthreads();
    }
    int ex = (t < 128) ? (cnt[t] - orig) : 0;
    if (t < 128) {
        int node = b * 128 + t;
        if (node < N) rowptr[node] = lo + ex;
    }
    __syncthreads();
    if (t < 128) cnt[t] = ex; // reuse as cursor
    __syncthreads();
    for (int e = lo + t; e < hi; e += 256) {
        uint2 p = pairs[e];
        int slot = atomicAdd(&cnt[p.y & 127], 1);
        colidx[lo + slot] = (int)p.x;
    }
}

// coeff from striped stats [8][256]: a = g*rsqrt(var+eps), c = b - mean*a
__device__ inline void coeff_from_stats(const float* __restrict__ stats,
                                        const float* __restrict__ g,
                                        const float* __restrict__ bb,
                                        int col, int N, float& a, float& c) {
    float s = 0.f, q = 0.f;
#pragma unroll
    for (int st = 0; st < 8; ++st) {
        s += stats[st * 256 + col];
        q += stats[st * 256 + 128 + col];
    }
    float m = s / N, v = q / N - m * m;
    a = g[col] * rsqrtf(v + BN_EPS);
    c = bb[col] - m * a;
}

// folded bn2+bn3 coeffs: f(u) = relu(a3*relu(a2u+c2)+c3) = max(A*u+C, D), a2,a3>0
// cfTab: A[128], C[128], D[128]
__global__ __launch_bounds__(128) void coeffF_kernel(
    const float* __restrict__ stats2, const float* __restrict__ g2, const float* __restrict__ b2v,
    const float* __restrict__ stats3, const float* __restrict__ g3, const float* __restrict__ b3v,
    float* __restrict__ cfTab, int N) {
    int col = threadIdx.x;
    float a2, c2, a3, c3;
    coeff_from_stats(stats2, g2, b2v, col, N, a2, c2);
    coeff_from_stats(stats3, g3, b3v, col, N, a3, c3);
    cfTab[col] = a3 * a2;
    cfTab[128 + col] = fmaf(a3, c2, c3);
    cfTab[256 + col] = fmaxf(c3, 0.f);
}

// ---------------- column-sliced aggregation ----------------
// rst[i] = f(x[i]) + sum_j f(x[j]); X bf16. slice = blockIdx&3 (32 cols, 64 B = 1 line):
// XCD-affine so each XCD's L2 holds one 3.2 MB slice. Wave = 1 node; 4 lane-groups of 16
// process 4 edges/iteration; cross-group shfl reduction at the end.
// MODE 0: f=identity. MODE 1: f(u)=max(A*u+C, D) from cfTab.

template <int MODE>
__global__ __launch_bounds__(256) void agg_kernel(
    const unsigned short* __restrict__ Xb, const int* __restrict__ rowptr,
    const int* __restrict__ colidx, const float* __restrict__ cfTab,
    float* __restrict__ rst, int N) {
    int t = threadIdx.x;
    int wv = t >> 6, lane = t & 63;
    int slice = blockIdx.x & 3;
    int node = (blockIdx.x >> 2) * 4 + wv;
    if (node >= N) return;
    int g = lane >> 4;
    int li = lane & 15;
    int cidx = slice * 16 + li; // ushort2 index within row (cols 2*cidx, 2*cidx+1)
    float A0 = 1.f, C0 = 0.f, D0 = 0.f, A1 = 1.f, C1 = 0.f, D1 = 0.f;
    if (MODE) {
        int c0 = cidx * 2;
        A0 = cfTab[c0];     A1 = cfTab[c0 + 1];
        C0 = cfTab[128 + c0]; C1 = cfTab[129 + c0];
        D0 = cfTab[256 + c0]; D1 = cfTab[257 + c0];
    }
    auto fx = [&](float u) { return MODE ? fmaxf(fmaf(A0, u, C0), D0) : u; };
    auto fy = [&](float u) { return MODE ? fmaxf(fmaf(A1, u, C1), D1) : u; };
    const ushort2* X2 = (const ushort2*)Xb;
    float ax = 0.f, ay = 0.f;
    if (g == 0) {
        ushort2 sv = X2[(size_t)node * 64 + cidx];
        ax = fx(bf2f((short)sv.x));
        ay = fy(bf2f((short)sv.y));
    }
    int e0 = rowptr[node], e1 = rowptr[node + 1];
    int eb = e0;
    for (; eb + 16 <= e1; eb += 16) {
        int j0 = colidx[eb + g];
        int j1 = colidx[eb + 4 + g];
        int j2 = colidx[eb + 8 + g];
        int j3 = colidx[eb + 12 + g];
        ushort2 v0 = X2[(size_t)j0 * 64 + cidx];
        ushort2 v1 = X2[(size_t)j1 * 64 + cidx];
        ushort2 v2 = X2[(size_t)j2 * 64 + cidx];
        ushort2 v3 = X2[(size_t)j3 * 64 + cidx];
        ax += fx(bf2f((short)v0.x)) + fx(bf2f((short)v1.x))
            + fx(bf2f((short)v2.x)) + fx(bf2f((short)v3.x));
        ay += fy(bf2f((short)v0.y)) + fy(bf2f((short)v1.y))
            + fy(bf2f((short)v2.y)) + fy(bf2f((short)v3.y));
    }
    for (int e = eb + g; e < e1; e += 4) {
        int j = colidx[e];
        ushort2 v = X2[(size_t)j * 64 + cidx];
        ax += fx(bf2f((short)v.x));
        ay += fy(bf2f((short)v.y));
    }
    ax += __shfl_xor(ax, 16, 64);
    ax += __shfl_xor(ax, 32, 64);
    ay += __shfl_xor(ay, 16, 64);
    ay += __shfl_xor(ay, 32, 64);
    if (lane < 16) {
        float2 r; r.x = ax; r.y = ay;
        ((float2*)rst)[(size_t)node * 64 + cidx] = r;
    }
}

// ---------------- GEMM: C = pre(A) @ W + bias, striped column stats ----------------

template <int PRE, int OUTBF>
__global__ __launch_bounds__(256, 2) void gemm_kernel(
    const float* __restrict__ A,
    const short* __restrict__ WtHi, const short* __restrict__ WtLo,
    const float* __restrict__ bias,
    const float* __restrict__ preStats, const float* __restrict__ preG,
    const float* __restrict__ preB,
    float* __restrict__ C, unsigned short* __restrict__ Cb,
    float* __restrict__ outStats, int N) {
    __shared__ short WsHi[128 * 128];
    __shared__ short WsLo[128 * 128];

    const int t = threadIdx.x;
    const int row0 = blockIdx.x * 128;
    const int w = t >> 6, lane = t & 63;
    const int quad = lane >> 4, l16 = lane & 15;
    const int sw = (l16 & 7) * 8;

    float aE = 1.f, cE = 0.f, aO = 1.f, cO = 0.f;
    if (PRE) {
        coeff_from_stats(preStats, preG, preB, lane * 2, N, aE, cE);
        coeff_from_stats(preStats, preG, preB, lane * 2 + 1, N, aO, cO);
    }

    float4 af[2][4][2];
#pragma unroll
    for (int m = 0; m < 2; ++m) {
        int gr = row0 + w * 32 + m * 16 + l16;
        bool ok = gr < N;
        const float* Ar = A + (size_t)gr * 128;
#pragma unroll
        for (int kk = 0; kk < 4; ++kk) {
            int kb = kk * 32 + quad * 8;
            af[m][kk][0] = ok ? *(const float4*)(Ar + kb) : make_float4(0.f, 0.f, 0.f, 0.f);
            af[m][kk][1] = ok ? *(const float4*)(Ar + kb + 4) : make_float4(0.f, 0.f, 0.f, 0.f);
        }
    }

#pragma unroll
    for (int i = 0; i < 8; ++i) {
        int ch = t + i * 256;
        int r = ch >> 4, k = (ch & 15) * 8;
        int d = r * 128 + (k ^ ((r & 7) * 8));
        *(short8*)(WsHi + d) = *(const short8*)(WtHi + r * 128 + k);
        *(short8*)(WsLo + d) = *(const short8*)(WtLo + r * 128 + k);
    }
    __syncthreads();

    short8 fh[2][4], fl[2][4];
#pragma unroll
    for (int kk = 0; kk < 4; ++kk) {
        float a8[8], c8[8];
#pragma unroll
        for (int j = 0; j < 8; ++j) {
            if (PRE) {
                int col = kk * 32 + quad * 8 + j;
                int srcl = col >> 1;
                a8[j] = __shfl((j & 1) ? aO : aE, srcl, 64);
                c8[j] = __shfl((j & 1) ? cO : cE, srcl, 64);
            }
        }
#pragma unroll
        for (int m = 0; m < 2; ++m) {
            float x[8];
            *(float4*)(x) = af[m][kk][0];
            *(float4*)(x + 4) = af[m][kk][1];
            short8 h, lo;
#pragma unroll
            for (int j = 0; j < 4; ++j) {
                float x0 = x[2 * j], x1 = x[2 * j + 1];
                if (PRE) {
                    x0 = fmaxf(a8[2 * j] * x0 + c8[2 * j], 0.f);
                    x1 = fmaxf(a8[2 * j + 1] * x1 + c8[2 * j + 1], 0.f);
                }
                unsigned u0 = asu(x0), u1 = asu(x1);
                unsigned hp = __builtin_amdgcn_perm(u1, u0, 0x07060302u);
                float l0 = x0 - asf(u0 & 0xFFFF0000u);
                float l1 = x1 - asf(u1 & 0xFFFF0000u);
                unsigned lp = __builtin_amdgcn_perm(asu(l1), asu(l0), 0x07060302u);
                ((unsigned*)&h)[j] = hp;
                ((unsigned*)&lo)[j] = lp;
            }
            fh[m][kk] = h;
            fl[m][kk] = lo;
        }
    }

    f32x4 acc[2][8];
#pragma unroll
    for (int m = 0; m < 2; ++m)
#pragma unroll
        for (int n = 0; n < 8; ++n) acc[m][n] = (f32x4){0.f, 0.f, 0.f, 0.f};

#pragma unroll
    for (int kk = 0; kk < 4; ++kk) {
        int kb = kk * 32 + quad * 8;
        bf16x8 a0h = __builtin_bit_cast(bf16x8, fh[0][kk]);
        bf16x8 a1h = __builtin_bit_cast(bf16x8, fh[1][kk]);
        bf16x8 a0l = __builtin_bit_cast(bf16x8, fl[0][kk]);
        bf16x8 a1l = __builtin_bit_cast(bf16x8, fl[1][kk]);
#pragma unroll
        for (int n = 0; n < 8; ++n) {
            int woff = (n * 16 + l16) * 128 + (kb ^ sw);
            bf16x8 bh = __builtin_bit_cast(bf16x8, *(const short8*)(WsHi + woff));
            bf16x8 bl = __builtin_bit_cast(bf16x8, *(const short8*)(WsLo + woff));
            acc[0][n] = __builtin_amdgcn_mfma_f32_16x16x32_bf16(a0h, bh, acc[0][n], 0, 0, 0);
            acc[0][n] = __builtin_amdgcn_mfma_f32_16x16x32_bf16(a0l, bh, acc[0][n], 0, 0, 0);
            acc[0][n] = __builtin_amdgcn_mfma_f32_16x16x32_bf16(a0h, bl, acc[0][n], 0, 0, 0);
            acc[1][n] = __builtin_amdgcn_mfma_f32_16x16x32_bf16(a1h, bh, acc[1][n], 0, 0, 0);
            acc[1][n] = __builtin_amdgcn_mfma_f32_16x16x32_bf16(a1l, bh, acc[1][n], 0, 0, 0);
            acc[1][n] = __builtin_amdgcn_mfma_f32_16x16x32_bf16(a1h, bl, acc[1][n], 0, 0, 0);
        }
    }

    __syncthreads(); // all LDS reads done; WsHi reused below for stats reduction

    float bv[8];
#pragma unroll
    for (int n = 0; n < 8; ++n) bv[n] = bias[n * 16 + l16];
    float ls[8], lsq[8];
#pragma unroll
    for (int n = 0; n < 8; ++n) { ls[n] = 0.f; lsq[n] = 0.f; }
#pragma unroll
    for (int m = 0; m < 2; ++m) {
        int rbase = row0 + w * 32 + m * 16 + quad * 4;
#pragma unroll
        for (int n = 0; n < 8; ++n) {
            int colv = n * 16 + l16;
#pragma unroll
            for (int r = 0; r < 4; ++r) {
                int row = rbase + r;
                if (row < N) {
                    float val = acc[m][n][r] + bv[n];
                    if (OUTBF) {
                        short hb = f2bf(val);
                        float vr = bf2f(hb);
                        Cb[(size_t)row * 128 + colv] = (unsigned short)hb;
                        ls[n] += vr;
                        lsq[n] += vr * vr;
                    } else {
                        C[(size_t)row * 128 + colv] = val;
                        ls[n] += val;
                        lsq[n] += val * val;
                    }
                }
            }
        }
    }

    float* P = (float*)WsHi;
#pragma unroll
    for (int n = 0; n < 8; ++n) {
        float s = ls[n], q = lsq[n];
        s += __shfl_xor(s, 16, 64);
        s += __shfl_xor(s, 32, 64);
        q += __shfl_xor(q, 16, 64);
        q += __shfl_xor(q, 32, 64);
        if (quad == 0) {
            int colv = n * 16 + l16;
            P[w * 512 + colv] = s;
            P[w * 512 + 256 + colv] = q;
        }
    }
    __syncthreads();

    int stripe = blockIdx.x & 7;
    if (t < 128) {
        int col = t;
        float S = P[col] + P[512 + col] + P[1024 + col] + P[1536 + col];
        atomicAdd(&outStats[stripe * 256 + col], S);
    } else {
        int col = t - 128;
        float Q = P[256 + col] + P[768 + col] + P[1280 + col] + P[1792 + col];
        atomicAdd(&outStats[stripe * 256 + 128 + col], Q);
    }
}

// ---------------- stats of y = relu(a*x+c) over bf16 X (no materialization) ----------------

__global__ __launch_bounds__(256) void elt_kernel(
    const unsigned short* __restrict__ Xb,
    const float* __restrict__ inStats, const float* __restrict__ g, const float* __restrict__ bb,
    float* __restrict__ outStats, int N) {
    __shared__ float red[256 * 8];
    __shared__ float cf[2][128];
    int t = threadIdx.x;
    if (t < 128) {
        float a, c;
        coeff_from_stats(inStats, g, bb, t, N, a, c);
        cf[0][t] = a; cf[1][t] = c;
    }
    __syncthreads();
    int cg = t & 31;
    float a[4], c[4];
#pragma unroll
    for (int k = 0; k < 4; ++k) {
        a[k] = cf[0][cg * 4 + k];
        c[k] = cf[1][cg * 4 + k];
    }
    float sum[4] = {0.f, 0.f, 0.f, 0.f}, sq[4] = {0.f, 0.f, 0.f, 0.f};
    int total = N * 32;
    for (int i = blockIdx.x * 256 + t; i < total; i += gridDim.x * 256) {
        ushort4 u = ((const ushort4*)Xb)[i];
        float y0 = fmaxf(a[0] * bf2f((short)u.x) + c[0], 0.f);
        float y1 = fmaxf(a[1] * bf2f((short)u.y) + c[1], 0.f);
        float y2 = fmaxf(a[2] * bf2f((short)u.z) + c[2], 0.f);
        float y3 = fmaxf(a[3] * bf2f((short)u.w) + c[3], 0.f);
        sum[0] += y0; sq[0] += y0 * y0;
        sum[1] += y1; sq[1] += y1 * y1;
        sum[2] += y2; sq[2] += y2 * y2;
        sum[3] += y3; sq[3] += y3 * y3;
    }
#pragma unroll
    for (int k = 0; k < 4; ++k) { red[t * 8 + k] = sum[k]; red[t * 8 + 4 + k] = sq[k]; }
    __syncthreads();
    if (t < 32) {
        float S[4] = {0.f, 0.f, 0.f, 0.f}, Q[4] = {0.f, 0.f, 0.f, 0.f};
        for (int j = 0; j < 8; ++j) {
            int tt = t + 32 * j;
#pragma unroll
            for (int k = 0; k < 4; ++k) { S[k] += red[tt * 8 + k]; Q[k] += red[tt * 8 + 4 + k]; }
        }
        int stripe = blockIdx.x & 7;
#pragma unroll
        for (int k = 0; k < 4; ++k) {
            atomicAdd(&outStats[stripe * 256 + t * 4 + k], S[k]);
            atomicAdd(&outStats[stripe * 256 + 128 + t * 4 + k], Q[k]);
        }
    }
}

// ---------------- final: out = max(A*x+C, D) from bf16 X, folded coeffs ----------------

__global__ __launch_bounds__(256) void final_kernel(
    const unsigned short* __restrict__ Xb, const float* __restrict__ cfTab,
    float* __restrict__ out, int N) {
    int t = threadIdx.x;
    int cg = t & 31;
    float A[4], C[4], D[4];
#pragma unroll
    for (int k = 0; k < 4; ++k) {
        int colv = cg * 4 + k;
        A[k] = cfTab[colv];
        C[k] = cfTab[128 + colv];
        D[k] = cfTab[256 + colv];
    }
    int total = N * 32;
    for (int i = blockIdx.x * 256 + t; i < total; i += gridDim.x * 256) {
        ushort4 u = ((const ushort4*)Xb)[i];
        float4 y;
        y.x = fmaxf(fmaf(A[0], bf2f((short)u.x), C[0]), D[0]);
        y.y = fmaxf(fmaf(A[1], bf2f((short)u.y), C[1]), D[1]);
        y.z = fmaxf(fmaf(A[2], bf2f((short)u.z), C[2]), D[2]);
        y.w = fmaxf(fmaf(A[3], bf2f((short)u.w), C[3]), D[3]);
        ((float4*)out)[i] = y;
    }
}

// ---------------- launch ----------------

extern "C" void kernel_launch(void* const* d_in, const int* in_sizes, int n_in,
                              void* d_out, int out_size, void* d_ws, size_t ws_size,
                              hipStream_t stream) {
    const float* h0   = (const float*)d_in[0];
    const int*   src  = (const int*)d_in[1];
    const int*   dst  = (const int*)d_in[2];
    const float* W1   = (const float*)d_in[3];
    const float* b1   = (const float*)d_in[4];
    const float* W2   = (const float*)d_in[5];
    const float* b2   = (const float*)d_in[6];
    const float* bn1g = (const float*)d_in[7];
    const float* bn1b = (const float*)d_in[8];
    const float* bn2g = (const float*)d_in[9];
    const float* bn2b = (const float*)d_in[10];
    const float* bn3g = (const float*)d_in[11];
    const float* bn3b = (const float*)d_in[12];
    const int N = in_sizes[0] / 128;
    const int E = in_sizes[1];
    const int nb = (N + 127) >> CSR_SHIFT;

    char* ws = (char*)d_ws;
    size_t off = 0;
    auto alloc = [&](size_t bytes) {
        void* p = ws + off;
        off = (off + bytes + 255) & ~(size_t)255;
        return p;
    };
    float* stats        = (float*)alloc((size_t)5 * 3 * 8 * 256 * sizeof(float)); // striped
    float* cfTab        = (float*)alloc((size_t)5 * 3 * 128 * sizeof(float));     // A,C,D folded
    int*   bucketCnt    = (int*)alloc((size_t)NBMAX * 4);
    int*   bucketBase   = (int*)alloc((size_t)(NBMAX + 1) * 4);
    int*   bucketCursor = (int*)alloc((size_t)NBMAX * 4);
    int*   rowptr       = (int*)alloc((size_t)(N + 1) * 4);
    int*   colidx       = (int*)alloc((size_t)E * 4);
    uint2* pairs        = (uint2*)alloc((size_t)E * 8);
    short* WtHi         = (short*)alloc((size_t)10 * 16384 * 2);
    short* WtLo         = (short*)alloc((size_t)10 * 16384 * 2);
    float* buf0         = (float*)alloc((size_t)N * 128 * 4);          // rst (f32)
    float* buf1         = (float*)alloc((size_t)N * 128 * 4);          // x1 (f32)
    unsigned short* xbf = (unsigned short*)alloc((size_t)N * 128 * 2); // h0/x2 (bf16)

    auto statsBase = [&](int l, int which) { return stats + ((size_t)(l * 3 + which)) * 8 * 256; };
    auto cfBase    = [&](int l) { return cfTab + (size_t)l * 3 * 128; };

    const int nstats = 5 * 3 * 8 * 256;
    int total4 = N * 32;
    setup_kernel<<<(total4 + 255) / 256, 256, 0, stream>>>(
        h0, xbf, total4, W1, W2, WtHi, WtLo, stats, nstats, bucketCnt, nb);

    const int chunk = 4096;
    const int chunkGrid = (E + chunk - 1) / chunk;
    bcount_kernel<<<chunkGrid, 256, 0, stream>>>(dst, bucketCnt, E, nb, chunk);
    bscan_kernel<<<1, 512, 0, stream>>>(bucketCnt, bucketBase, bucketCursor, rowptr, nb, N, E);
    bscatter_kernel<<<chunkGrid, 256, 0, stream>>>(src, dst, bucketCursor, pairs, E, nb, chunk);
    bbuild_kernel<<<nb, 256, 0, stream>>>(pairs, bucketBase, rowptr, colidx, N);

    const int gemmGrid = (N + 127) / 128;
    const int aggGrid = ((N + 3) / 4) * 4; // node-group x 4 slices
    for (int l = 0; l < 5; ++l) {
        if (l == 0) {
            agg_kernel<0><<<aggGrid, 256, 0, stream>>>(
                xbf, rowptr, colidx, nullptr, buf0, N);
        } else {
            agg_kernel<1><<<aggGrid, 256, 0, stream>>>(
                xbf, rowptr, colidx, cfBase(l - 1), buf0, N);
        }
        gemm_kernel<0, 0><<<gemmGrid, 256, 0, stream>>>(
            buf0, WtHi + l * 16384, WtLo + l * 16384, b1 + l * 128,
            nullptr, nullptr, nullptr,
            buf1, nullptr, statsBase(l, 0), N);
        gemm_kernel<1, 1><<<gemmGrid, 256, 0, stream>>>(
            buf1, WtHi + (5 + l) * 16384, WtLo + (5 + l) * 16384, b2 + l * 128,
            statsBase(l, 0), bn1g + l * 128, bn1b + l * 128,
            nullptr, xbf, statsBase(l, 1), N);
        elt_kernel<<<256, 256, 0, stream>>>(
            xbf, statsBase(l, 1), bn2g + l * 128, bn2b + l * 128,
            statsBase(l, 2), N);
        coeffF_kernel<<<1, 128, 0, stream>>>(
            statsBase(l, 1), bn2g + l * 128, bn2b + l * 128,
            statsBase(l, 2), bn3g + l * 128, bn3b + l * 128,
            cfBase(l), N);
    }
    final_kernel<<<512, 256, 0, stream>>>(xbf, cfBase(4), (float*)d_out, N);
}

// Round 9
// 558.404 us; speedup vs baseline: 1.4973x; 1.4973x over previous
//
#include <hip/hip_runtime.h>
#include <hip/hip_bf16.h>
#include <cstdint>

#define BN_EPS 1e-5f
#define CSR_SHIFT 7
#define NBMAX 512

typedef __attribute__((ext_vector_type(8))) short short8;
typedef __attribute__((ext_vector_type(8))) __bf16 bf16x8;
typedef __attribute__((ext_vector_type(4))) float f32x4;

__device__ inline short f2bf(float f) {
    union { float f; unsigned u; } v; v.f = f;
    unsigned r = v.u + 0x7fffu + ((v.u >> 16) & 1u); // RNE
    return (short)(r >> 16);
}
__device__ inline float bf2f(short h) {
    union { unsigned u; float f; } v;
    v.u = ((unsigned)(unsigned short)h) << 16;
    return v.f;
}
__device__ inline unsigned asu(float f) { union { float f; unsigned u; } v; v.f = f; return v.u; }
__device__ inline float asf(unsigned u) { union { unsigned u; float f; } v; v.u = u; return v.f; }

// ---------------- fused setup: zero stats/bucketCnt, h0->bf16, weight split ----------------

__global__ __launch_bounds__(256) void setup_kernel(
    const float* __restrict__ h, unsigned short* __restrict__ hb, int total4,
    const float* __restrict__ W1, const float* __restrict__ W2,
    short* __restrict__ WtHi, short* __restrict__ WtLo,
    float* __restrict__ stats, int nstats, int* __restrict__ bcnt, int nb) {
    int i = blockIdx.x * 256 + threadIdx.x;
    if (i < nstats) stats[i] = 0.f;
    if (i < nb) bcnt[i] = 0;
    if (i < 10 * 128 * 128) {
        int mat = i >> 14, n = (i >> 7) & 127, k = i & 127;
        const float* W = (mat < 5) ? (W1 + mat * 16384) : (W2 + (mat - 5) * 16384);
        float w = W[k * 128 + n];
        short hi = f2bf(w);
        WtHi[i] = hi;
        WtLo[i] = f2bf(w - bf2f(hi));
    }
    if (i < total4) {
        float4 v = ((const float4*)h)[i];
        ushort4 o;
        o.x = (unsigned short)f2bf(v.x);
        o.y = (unsigned short)f2bf(v.y);
        o.z = (unsigned short)f2bf(v.z);
        o.w = (unsigned short)f2bf(v.w);
        ((ushort4*)hb)[i] = o;
    }
}

// ---- bucketed CSR build: bucket = dst >> 7 (128 nodes/bucket) ----

__global__ __launch_bounds__(256) void bcount_kernel(const int* __restrict__ dst,
                                                     int* __restrict__ bucketCnt,
                                                     int E, int nb, int chunk) {
    __shared__ int hist[NBMAX];
    int t = threadIdx.x;
    for (int i = t; i < nb; i += 256) hist[i] = 0;
    __syncthreads();
    int s = blockIdx.x * chunk, e = s + chunk; if (e > E) e = E;
    for (int i = s + t; i < e; i += 256) atomicAdd(&hist[dst[i] >> CSR_SHIFT], 1);
    __syncthreads();
    for (int i = t; i < nb; i += 256) if (hist[i]) atomicAdd(&bucketCnt[i], hist[i]);
}

__global__ __launch_bounds__(512) void bscan_kernel(const int* __restrict__ bucketCnt,
                                                    int* __restrict__ bucketBase,
                                                    int* __restrict__ bucketCursor,
                                                    int* __restrict__ rowptr,
                                                    int nb, int N, int E) {
    __shared__ int ps[NBMAX];
    int t = threadIdx.x;
    int v = (t < nb) ? bucketCnt[t] : 0;
    ps[t] = v;
    __syncthreads();
#pragma unroll
    for (int off = 1; off < NBMAX; off <<= 1) {
        int u = 0;
        if (t >= off) u = ps[t - off];
        __syncthreads();
        ps[t] += u;
        __syncthreads();
    }
    if (t < nb) {
        int b = ps[t] - v; // exclusive
        bucketBase[t] = b;
        bucketCursor[t] = b;
    }
    if (t == 0) { bucketBase[nb] = E; rowptr[N] = E; }
}

__global__ __launch_bounds__(256) void bscatter_kernel(const int* __restrict__ src,
                                                       const int* __restrict__ dst,
                                                       int* __restrict__ bucketCursor,
                                                       uint2* __restrict__ pairs,
                                                       int E, int nb, int chunk) {
    __shared__ int cnt[NBMAX];
    __shared__ int base[NBMAX];
    int t = threadIdx.x;
    for (int i = t; i < nb; i += 256) cnt[i] = 0;
    __syncthreads();
    int s = blockIdx.x * chunk, e = s + chunk; if (e > E) e = E;
    for (int i = s + t; i < e; i += 256) atomicAdd(&cnt[dst[i] >> CSR_SHIFT], 1);
    __syncthreads();
    for (int i = t; i < nb; i += 256) {
        int c = cnt[i];
        base[i] = c ? atomicAdd(&bucketCursor[i], c) : 0;
    }
    __syncthreads();
    for (int i = t; i < nb; i += 256) cnt[i] = 0;
    __syncthreads();
    for (int i = s + t; i < e; i += 256) {
        int d = dst[i];
        int b = d >> CSR_SHIFT;
        int slot = atomicAdd(&cnt[b], 1);
        pairs[base[b] + slot] = make_uint2((unsigned)src[i], (unsigned)d);
    }
}

__global__ __launch_bounds__(256) void bbuild_kernel(const uint2* __restrict__ pairs,
                                                     const int* __restrict__ bucketBase,
                                                     int* __restrict__ rowptr,
                                                     int* __restrict__ colidx, int N) {
    __shared__ int cnt[128];
    int b = blockIdx.x, t = threadIdx.x;
    int lo = bucketBase[b], hi = bucketBase[b + 1];
    if (t < 128) cnt[t] = 0;
    __syncthreads();
    for (int e = lo + t; e < hi; e += 256) atomicAdd(&cnt[pairs[e].y & 127], 1);
    __syncthreads();
    int orig = (t < 128) ? cnt[t] : 0;
#pragma unroll
    for (int o = 1; o < 128; o <<= 1) {
        int u = 0;
        if (t < 128 && t >= o) u = cnt[t - o];
        __syncthreads();
        if (t < 128) cnt[t] += u;
        __syncthreads();
    }
    int ex = (t < 128) ? (cnt[t] - orig) : 0;
    if (t < 128) {
        int node = b * 128 + t;
        if (node < N) rowptr[node] = lo + ex;
    }
    __syncthreads();
    if (t < 128) cnt[t] = ex; // reuse as cursor
    __syncthreads();
    for (int e = lo + t; e < hi; e += 256) {
        uint2 p = pairs[e];
        int slot = atomicAdd(&cnt[p.y & 127], 1);
        colidx[lo + slot] = (int)p.x;
    }
}

// coeff from striped stats [8][256]: a = g*rsqrt(var+eps), c = b - mean*a
__device__ inline void coeff_from_stats(const float* __restrict__ stats,
                                        const float* __restrict__ g,
                                        const float* __restrict__ bb,
                                        int col, int N, float& a, float& c) {
    float s = 0.f, q = 0.f;
#pragma unroll
    for (int st = 0; st < 8; ++st) {
        s += stats[st * 256 + col];
        q += stats[st * 256 + 128 + col];
    }
    float m = s / N, v = q / N - m * m;
    a = g[col] * rsqrtf(v + BN_EPS);
    c = bb[col] - m * a;
}

// folded bn2+bn3 coeffs: f(u) = relu(a3*relu(a2u+c2)+c3) = max(A*u+C, D), a2,a3>0
// cfTab: A[128], C[128], D[128]
__global__ __launch_bounds__(128) void coeffF_kernel(
    const float* __restrict__ stats2, const float* __restrict__ g2, const float* __restrict__ b2v,
    const float* __restrict__ stats3, const float* __restrict__ g3, const float* __restrict__ b3v,
    float* __restrict__ cfTab, int N) {
    int col = threadIdx.x;
    float a2, c2, a3, c3;
    coeff_from_stats(stats2, g2, b2v, col, N, a2, c2);
    coeff_from_stats(stats3, g3, b3v, col, N, a3, c3);
    cfTab[col] = a3 * a2;
    cfTab[128 + col] = fmaf(a3, c2, c3);
    cfTab[256 + col] = fmaxf(c3, 0.f);
}

// ---------------- aggregation: rst[i] = f(x[i]) + sum_{j in in(i)} f(x[j]) ----------------
// X bf16. One wave per node (whole 256 B row per gather, full line utilization).
// MODE 0: f = identity. MODE 1: f(u) = max(A*u+C, D) from folded cfTab. Edge unroll 16/4/1.

template <int MODE>
__global__ __launch_bounds__(256) void agg_kernel(
    const unsigned short* __restrict__ Xb, const int* __restrict__ rowptr,
    const int* __restrict__ colidx, const float* __restrict__ cfTab,
    float* __restrict__ rst, int N) {
    int t = threadIdx.x;
    int node = (blockIdx.x * 256 + t) >> 6;
    if (node >= N) return;
    int lane = t & 63;
    int c0 = lane * 2, c1 = c0 + 1;
    float A0 = 1.f, C0 = 0.f, D0 = 0.f, A1 = 1.f, C1 = 0.f, D1 = 0.f;
    if (MODE) {
        A0 = cfTab[c0];       A1 = cfTab[c1];
        C0 = cfTab[128 + c0]; C1 = cfTab[128 + c1];
        D0 = cfTab[256 + c0]; D1 = cfTab[256 + c1];
    }
    auto fx = [&](float u) { return MODE ? fmaxf(fmaf(A0, u, C0), D0) : u; };
    auto fy = [&](float u) { return MODE ? fmaxf(fmaf(A1, u, C1), D1) : u; };
    const ushort2* X2 = (const ushort2*)Xb;
    ushort2 self = X2[(size_t)node * 64 + lane];
    float ax = fx(bf2f((short)self.x)), ay = fy(bf2f((short)self.y));
    int e = rowptr[node], end = rowptr[node + 1];
    for (; e + 16 <= end; e += 16) {
        int j[16];
#pragma unroll
        for (int k = 0; k < 16; ++k) j[k] = colidx[e + k];
        ushort2 v[16];
#pragma unroll
        for (int k = 0; k < 16; ++k) v[k] = X2[(size_t)j[k] * 64 + lane];
#pragma unroll
        for (int k = 0; k < 16; ++k) {
            ax += fx(bf2f((short)v[k].x));
            ay += fy(bf2f((short)v[k].y));
        }
    }
    for (; e + 4 <= end; e += 4) {
        int j[4];
#pragma unroll
        for (int k = 0; k < 4; ++k) j[k] = colidx[e + k];
        ushort2 v[4];
#pragma unroll
        for (int k = 0; k < 4; ++k) v[k] = X2[(size_t)j[k] * 64 + lane];
#pragma unroll
        for (int k = 0; k < 4; ++k) {
            ax += fx(bf2f((short)v[k].x));
            ay += fy(bf2f((short)v[k].y));
        }
    }
    for (; e < end; ++e) {
        int j = colidx[e];
        ushort2 v = X2[(size_t)j * 64 + lane];
        ax += fx(bf2f((short)v.x));
        ay += fy(bf2f((short)v.y));
    }
    float2 r; r.x = ax; r.y = ay;
    ((float2*)rst)[(size_t)node * 64 + lane] = r;
}

// ---------------- GEMM: C = pre(A) @ W + bias, striped column stats ----------------
// W hi/lo staged in LDS (XOR-swizzled); A (f32) streamed global->registers.
// Split: hi = trunc16(x) (v_perm pack), lo = trunc16(x - hi) (exact sub + perm pack).
// PRE==1: relu(a*x+c), coeffs per-lane from striped stats redistributed via __shfl.
// OUTBF==1: write C as bf16 (RNE), stats on the rounded values.

template <int PRE, int OUTBF>
__global__ __launch_bounds__(256, 2) void gemm_kernel(
    const float* __restrict__ A,
    const short* __restrict__ WtHi, const short* __restrict__ WtLo,
    const float* __restrict__ bias,
    const float* __restrict__ preStats, const float* __restrict__ preG,
    const float* __restrict__ preB,
    float* __restrict__ C, unsigned short* __restrict__ Cb,
    float* __restrict__ outStats, int N) {
    __shared__ short WsHi[128 * 128];
    __shared__ short WsLo[128 * 128];

    const int t = threadIdx.x;
    const int row0 = blockIdx.x * 128;
    const int w = t >> 6, lane = t & 63;
    const int quad = lane >> 4, l16 = lane & 15;
    const int sw = (l16 & 7) * 8;

    float aE = 1.f, cE = 0.f, aO = 1.f, cO = 0.f;
    if (PRE) {
        coeff_from_stats(preStats, preG, preB, lane * 2, N, aE, cE);
        coeff_from_stats(preStats, preG, preB, lane * 2 + 1, N, aO, cO);
    }

    float4 af[2][4][2];
#pragma unroll
    for (int m = 0; m < 2; ++m) {
        int gr = row0 + w * 32 + m * 16 + l16;
        bool ok = gr < N;
        const float* Ar = A + (size_t)gr * 128;
#pragma unroll
        for (int kk = 0; kk < 4; ++kk) {
            int kb = kk * 32 + quad * 8;
            af[m][kk][0] = ok ? *(const float4*)(Ar + kb) : make_float4(0.f, 0.f, 0.f, 0.f);
            af[m][kk][1] = ok ? *(const float4*)(Ar + kb + 4) : make_float4(0.f, 0.f, 0.f, 0.f);
        }
    }

#pragma unroll
    for (int i = 0; i < 8; ++i) {
        int ch = t + i * 256;
        int r = ch >> 4, k = (ch & 15) * 8;
        int d = r * 128 + (k ^ ((r & 7) * 8));
        *(short8*)(WsHi + d) = *(const short8*)(WtHi + r * 128 + k);
        *(short8*)(WsLo + d) = *(const short8*)(WtLo + r * 128 + k);
    }
    __syncthreads();

    short8 fh[2][4], fl[2][4];
#pragma unroll
    for (int kk = 0; kk < 4; ++kk) {
        float a8[8], c8[8];
#pragma unroll
        for (int j = 0; j < 8; ++j) {
            if (PRE) {
                int col = kk * 32 + quad * 8 + j;
                int srcl = col >> 1;
                a8[j] = __shfl((j & 1) ? aO : aE, srcl, 64);
                c8[j] = __shfl((j & 1) ? cO : cE, srcl, 64);
            }
        }
#pragma unroll
        for (int m = 0; m < 2; ++m) {
            float x[8];
            *(float4*)(x) = af[m][kk][0];
            *(float4*)(x + 4) = af[m][kk][1];
            short8 h, lo;
#pragma unroll
            for (int j = 0; j < 4; ++j) {
                float x0 = x[2 * j], x1 = x[2 * j + 1];
                if (PRE) {
                    x0 = fmaxf(a8[2 * j] * x0 + c8[2 * j], 0.f);
                    x1 = fmaxf(a8[2 * j + 1] * x1 + c8[2 * j + 1], 0.f);
                }
                unsigned u0 = asu(x0), u1 = asu(x1);
                unsigned hp = __builtin_amdgcn_perm(u1, u0, 0x07060302u);
                float l0 = x0 - asf(u0 & 0xFFFF0000u);
                float l1 = x1 - asf(u1 & 0xFFFF0000u);
                unsigned lp = __builtin_amdgcn_perm(asu(l1), asu(l0), 0x07060302u);
                ((unsigned*)&h)[j] = hp;
                ((unsigned*)&lo)[j] = lp;
            }
            fh[m][kk] = h;
            fl[m][kk] = lo;
        }
    }

    f32x4 acc[2][8];
#pragma unroll
    for (int m = 0; m < 2; ++m)
#pragma unroll
        for (int n = 0; n < 8; ++n) acc[m][n] = (f32x4){0.f, 0.f, 0.f, 0.f};

#pragma unroll
    for (int kk = 0; kk < 4; ++kk) {
        int kb = kk * 32 + quad * 8;
        bf16x8 a0h = __builtin_bit_cast(bf16x8, fh[0][kk]);
        bf16x8 a1h = __builtin_bit_cast(bf16x8, fh[1][kk]);
        bf16x8 a0l = __builtin_bit_cast(bf16x8, fl[0][kk]);
        bf16x8 a1l = __builtin_bit_cast(bf16x8, fl[1][kk]);
#pragma unroll
        for (int n = 0; n < 8; ++n) {
            int woff = (n * 16 + l16) * 128 + (kb ^ sw);
            bf16x8 bh = __builtin_bit_cast(bf16x8, *(const short8*)(WsHi + woff));
            bf16x8 bl = __builtin_bit_cast(bf16x8, *(const short8*)(WsLo + woff));
            acc[0][n] = __builtin_amdgcn_mfma_f32_16x16x32_bf16(a0h, bh, acc[0][n], 0, 0, 0);
            acc[0][n] = __builtin_amdgcn_mfma_f32_16x16x32_bf16(a0l, bh, acc[0][n], 0, 0, 0);
            acc[0][n] = __builtin_amdgcn_mfma_f32_16x16x32_bf16(a0h, bl, acc[0][n], 0, 0, 0);
            acc[1][n] = __builtin_amdgcn_mfma_f32_16x16x32_bf16(a1h, bh, acc[1][n], 0, 0, 0);
            acc[1][n] = __builtin_amdgcn_mfma_f32_16x16x32_bf16(a1l, bh, acc[1][n], 0, 0, 0);
            acc[1][n] = __builtin_amdgcn_mfma_f32_16x16x32_bf16(a1h, bl, acc[1][n], 0, 0, 0);
        }
    }

    __syncthreads(); // all LDS reads done; WsHi reused below for stats reduction

    float bv[8];
#pragma unroll
    for (int n = 0; n < 8; ++n) bv[n] = bias[n * 16 + l16];
    float ls[8], lsq[8];
#pragma unroll
    for (int n = 0; n < 8; ++n) { ls[n] = 0.f; lsq[n] = 0.f; }
#pragma unroll
    for (int m = 0; m < 2; ++m) {
        int rbase = row0 + w * 32 + m * 16 + quad * 4;
#pragma unroll
        for (int n = 0; n < 8; ++n) {
            int colv = n * 16 + l16;
#pragma unroll
            for (int r = 0; r < 4; ++r) {
                int row = rbase + r;
                if (row < N) {
                    float val = acc[m][n][r] + bv[n];
                    if (OUTBF) {
                        short hb = f2bf(val);
                        float vr = bf2f(hb);
                        Cb[(size_t)row * 128 + colv] = (unsigned short)hb;
                        ls[n] += vr;
                        lsq[n] += vr * vr;
                    } else {
                        C[(size_t)row * 128 + colv] = val;
                        ls[n] += val;
                        lsq[n] += val * val;
                    }
                }
            }
        }
    }

    float* P = (float*)WsHi;
#pragma unroll
    for (int n = 0; n < 8; ++n) {
        float s = ls[n], q = lsq[n];
        s += __shfl_xor(s, 16, 64);
        s += __shfl_xor(s, 32, 64);
        q += __shfl_xor(q, 16, 64);
        q += __shfl_xor(q, 32, 64);
        if (quad == 0) {
            int colv = n * 16 + l16;
            P[w * 512 + colv] = s;
            P[w * 512 + 256 + colv] = q;
        }
    }
    __syncthreads();

    int stripe = blockIdx.x & 7;
    if (t < 128) {
        int col = t;
        float S = P[col] + P[512 + col] + P[1024 + col] + P[1536 + col];
        atomicAdd(&outStats[stripe * 256 + col], S);
    } else {
        int col = t - 128;
        float Q = P[256 + col] + P[768 + col] + P[1280 + col] + P[1792 + col];
        atomicAdd(&outStats[stripe * 256 + 128 + col], Q);
    }
}

// ---------------- stats of y = relu(a*x+c) over bf16 X (no materialization) ----------------

__global__ __launch_bounds__(256) void elt_kernel(
    const unsigned short* __restrict__ Xb,
    const float* __restrict__ inStats, const float* __restrict__ g, const float* __restrict__ bb,
    float* __restrict__ outStats, int N) {
    __shared__ float red[256 * 8];
    __shared__ float cf[2][128];
    int t = threadIdx.x;
    if (t < 128) {
        float a, c;
        coeff_from_stats(inStats, g, bb, t, N, a, c);
        cf[0][t] = a; cf[1][t] = c;
    }
    __syncthreads();
    int cg = t & 31;
    float a[4], c[4];
#pragma unroll
    for (int k = 0; k < 4; ++k) {
        a[k] = cf[0][cg * 4 + k];
        c[k] = cf[1][cg * 4 + k];
    }
    float sum[4] = {0.f, 0.f, 0.f, 0.f}, sq[4] = {0.f, 0.f, 0.f, 0.f};
    int total = N * 32;
    for (int i = blockIdx.x * 256 + t; i < total; i += gridDim.x * 256) {
        ushort4 u = ((const ushort4*)Xb)[i];
        float y0 = fmaxf(a[0] * bf2f((short)u.x) + c[0], 0.f);
        float y1 = fmaxf(a[1] * bf2f((short)u.y) + c[1], 0.f);
        float y2 = fmaxf(a[2] * bf2f((short)u.z) + c[2], 0.f);
        float y3 = fmaxf(a[3] * bf2f((short)u.w) + c[3], 0.f);
        sum[0] += y0; sq[0] += y0 * y0;
        sum[1] += y1; sq[1] += y1 * y1;
        sum[2] += y2; sq[2] += y2 * y2;
        sum[3] += y3; sq[3] += y3 * y3;
    }
#pragma unroll
    for (int k = 0; k < 4; ++k) { red[t * 8 + k] = sum[k]; red[t * 8 + 4 + k] = sq[k]; }
    __syncthreads();
    if (t < 32) {
        float S[4] = {0.f, 0.f, 0.f, 0.f}, Q[4] = {0.f, 0.f, 0.f, 0.f};
        for (int j = 0; j < 8; ++j) {
            int tt = t + 32 * j;
#pragma unroll
            for (int k = 0; k < 4; ++k) { S[k] += red[tt * 8 + k]; Q[k] += red[tt * 8 + 4 + k]; }
        }
        int stripe = blockIdx.x & 7;
#pragma unroll
        for (int k = 0; k < 4; ++k) {
            atomicAdd(&outStats[stripe * 256 + t * 4 + k], S[k]);
            atomicAdd(&outStats[stripe * 256 + 128 + t * 4 + k], Q[k]);
        }
    }
}

// ---------------- final: out = max(A*x+C, D) from bf16 X, folded coeffs ----------------

__global__ __launch_bounds__(256) void final_kernel(
    const unsigned short* __restrict__ Xb, const float* __restrict__ cfTab,
    float* __restrict__ out, int N) {
    int t = threadIdx.x;
    int cg = t & 31;
    float A[4], C[4], D[4];
#pragma unroll
    for (int k = 0; k < 4; ++k) {
        int colv = cg * 4 + k;
        A[k] = cfTab[colv];
        C[k] = cfTab[128 + colv];
        D[k] = cfTab[256 + colv];
    }
    int total = N * 32;
    for (int i = blockIdx.x * 256 + t; i < total; i += gridDim.x * 256) {
        ushort4 u = ((const ushort4*)Xb)[i];
        float4 y;
        y.x = fmaxf(fmaf(A[0], bf2f((short)u.x), C[0]), D[0]);
        y.y = fmaxf(fmaf(A[1], bf2f((short)u.y), C[1]), D[1]);
        y.z = fmaxf(fmaf(A[2], bf2f((short)u.z), C[2]), D[2]);
        y.w = fmaxf(fmaf(A[3], bf2f((short)u.w), C[3]), D[3]);
        ((float4*)out)[i] = y;
    }
}

// ---------------- launch ----------------

extern "C" void kernel_launch(void* const* d_in, const int* in_sizes, int n_in,
                              void* d_out, int out_size, void* d_ws, size_t ws_size,
                              hipStream_t stream) {
    const float* h0   = (const float*)d_in[0];
    const int*   src  = (const int*)d_in[1];
    const int*   dst  = (const int*)d_in[2];
    const float* W1   = (const float*)d_in[3];
    const float* b1   = (const float*)d_in[4];
    const float* W2   = (const float*)d_in[5];
    const float* b2   = (const float*)d_in[6];
    const float* bn1g = (const float*)d_in[7];
    const float* bn1b = (const float*)d_in[8];
    const float* bn2g = (const float*)d_in[9];
    const float* bn2b = (const float*)d_in[10];
    const float* bn3g = (const float*)d_in[11];
    const float* bn3b = (const float*)d_in[12];
    const int N = in_sizes[0] / 128;
    const int E = in_sizes[1];
    const int nb = (N + 127) >> CSR_SHIFT;

    char* ws = (char*)d_ws;
    size_t off = 0;
    auto alloc = [&](size_t bytes) {
        void* p = ws + off;
        off = (off + bytes + 255) & ~(size_t)255;
        return p;
    };
    float* stats        = (float*)alloc((size_t)5 * 3 * 8 * 256 * sizeof(float)); // striped
    float* cfTab        = (float*)alloc((size_t)5 * 3 * 128 * sizeof(float));     // A,C,D folded
    int*   bucketCnt    = (int*)alloc((size_t)NBMAX * 4);
    int*   bucketBase   = (int*)alloc((size_t)(NBMAX + 1) * 4);
    int*   bucketCursor = (int*)alloc((size_t)NBMAX * 4);
    int*   rowptr       = (int*)alloc((size_t)(N + 1) * 4);
    int*   colidx       = (int*)alloc((size_t)E * 4);
    uint2* pairs        = (uint2*)alloc((size_t)E * 8);
    short* WtHi         = (short*)alloc((size_t)10 * 16384 * 2);
    short* WtLo         = (short*)alloc((size_t)10 * 16384 * 2);
    float* buf0         = (float*)alloc((size_t)N * 128 * 4);          // rst (f32)
    float* buf1         = (float*)alloc((size_t)N * 128 * 4);          // x1 (f32)
    unsigned short* xbf = (unsigned short*)alloc((size_t)N * 128 * 2); // h0/x2 (bf16)

    auto statsBase = [&](int l, int which) { return stats + ((size_t)(l * 3 + which)) * 8 * 256; };
    auto cfBase    = [&](int l) { return cfTab + (size_t)l * 3 * 128; };

    const int nstats = 5 * 3 * 8 * 256;
    int total4 = N * 32;
    setup_kernel<<<(total4 + 255) / 256, 256, 0, stream>>>(
        h0, xbf, total4, W1, W2, WtHi, WtLo, stats, nstats, bucketCnt, nb);

    const int chunk = 4096;
    const int chunkGrid = (E + chunk - 1) / chunk;
    bcount_kernel<<<chunkGrid, 256, 0, stream>>>(dst, bucketCnt, E, nb, chunk);
    bscan_kernel<<<1, 512, 0, stream>>>(bucketCnt, bucketBase, bucketCursor, rowptr, nb, N, E);
    bscatter_kernel<<<chunkGrid, 256, 0, stream>>>(src, dst, bucketCursor, pairs, E, nb, chunk);
    bbuild_kernel<<<nb, 256, 0, stream>>>(pairs, bucketBase, rowptr, colidx, N);

    const int gemmGrid = (N + 127) / 128;
    const int aggGrid = (N + 3) / 4;
    for (int l = 0; l < 5; ++l) {
        if (l == 0) {
            agg_kernel<0><<<aggGrid, 256, 0, stream>>>(
                xbf, rowptr, colidx, nullptr, buf0, N);
        } else {
            agg_kernel<1><<<aggGrid, 256, 0, stream>>>(
                xbf, rowptr, colidx, cfBase(l - 1), buf0, N);
        }
        gemm_kernel<0, 0><<<gemmGrid, 256, 0, stream>>>(
            buf0, WtHi + l * 16384, WtLo + l * 16384, b1 + l * 128,
            nullptr, nullptr, nullptr,
            buf1, nullptr, statsBase(l, 0), N);
        gemm_kernel<1, 1><<<gemmGrid, 256, 0, stream>>>(
            buf1, WtHi + (5 + l) * 16384, WtLo + (5 + l) * 16384, b2 + l * 128,
            statsBase(l, 0), bn1g + l * 128, bn1b + l * 128,
            nullptr, xbf, statsBase(l, 1), N);
        elt_kernel<<<256, 256, 0, stream>>>(
            xbf, statsBase(l, 1), bn2g + l * 128, bn2b + l * 128,
            statsBase(l, 2), N);
        coeffF_kernel<<<1, 128, 0, stream>>>(
            statsBase(l, 1), bn2g + l * 128, bn2b + l * 128,
            statsBase(l, 2), bn3g + l * 128, bn3b + l * 128,
            cfBase(l), N);
    }
    final_kernel<<<512, 256, 0, stream>>>(xbf, cfBase(4), (float*)d_out, N);
}

// Round 10
// 535.329 us; speedup vs baseline: 1.5618x; 1.0431x over previous
//
#include <hip/hip_runtime.h>
#include <hip/hip_bf16.h>
#include <cstdint>

#define BN_EPS 1e-5f
#define CSR_SHIFT 7
#define NBMAX 512

typedef __attribute__((ext_vector_type(8))) short short8;
typedef __attribute__((ext_vector_type(8))) __bf16 bf16x8;
typedef __attribute__((ext_vector_type(4))) float f32x4;

__device__ inline short f2bf(float f) {
    union { float f; unsigned u; } v; v.f = f;
    unsigned r = v.u + 0x7fffu + ((v.u >> 16) & 1u); // RNE
    return (short)(r >> 16);
}
__device__ inline float bf2f(short h) {
    union { unsigned u; float f; } v;
    v.u = ((unsigned)(unsigned short)h) << 16;
    return v.f;
}
__device__ inline unsigned asu(float f) { union { float f; unsigned u; } v; v.f = f; return v.u; }
__device__ inline float asf(unsigned u) { union { unsigned u; float f; } v; v.u = u; return v.f; }

// ---------------- fused setup: zero stats/bucketCnt, h0->bf16, weight split ----------------

__global__ __launch_bounds__(256) void setup_kernel(
    const float* __restrict__ h, unsigned short* __restrict__ hb, int total4,
    const float* __restrict__ W1, const float* __restrict__ W2,
    short* __restrict__ WtHi, short* __restrict__ WtLo,
    float* __restrict__ stats, int nstats, int* __restrict__ bcnt, int nb) {
    int i = blockIdx.x * 256 + threadIdx.x;
    if (i < nstats) stats[i] = 0.f;
    if (i < nb) bcnt[i] = 0;
    if (i < 10 * 128 * 128) {
        int mat = i >> 14, n = (i >> 7) & 127, k = i & 127;
        const float* W = (mat < 5) ? (W1 + mat * 16384) : (W2 + (mat - 5) * 16384);
        float w = W[k * 128 + n];
        short hi = f2bf(w);
        WtHi[i] = hi;
        WtLo[i] = f2bf(w - bf2f(hi));
    }
    if (i < total4) {
        float4 v = ((const float4*)h)[i];
        ushort4 o;
        o.x = (unsigned short)f2bf(v.x);
        o.y = (unsigned short)f2bf(v.y);
        o.z = (unsigned short)f2bf(v.z);
        o.w = (unsigned short)f2bf(v.w);
        ((ushort4*)hb)[i] = o;
    }
}

// ---- bucketed CSR build: bucket = dst >> 7 (128 nodes/bucket) ----

__global__ __launch_bounds__(256) void bcount_kernel(const int* __restrict__ dst,
                                                     int* __restrict__ bucketCnt,
                                                     int E, int nb, int chunk) {
    __shared__ int hist[NBMAX];
    int t = threadIdx.x;
    for (int i = t; i < nb; i += 256) hist[i] = 0;
    __syncthreads();
    int s = blockIdx.x * chunk, e = s + chunk; if (e > E) e = E;
    for (int i = s + t; i < e; i += 256) atomicAdd(&hist[dst[i] >> CSR_SHIFT], 1);
    __syncthreads();
    for (int i = t; i < nb; i += 256) if (hist[i]) atomicAdd(&bucketCnt[i], hist[i]);
}

__global__ __launch_bounds__(512) void bscan_kernel(const int* __restrict__ bucketCnt,
                                                    int* __restrict__ bucketBase,
                                                    int* __restrict__ bucketCursor,
                                                    int* __restrict__ rowptr,
                                                    int nb, int N, int E) {
    __shared__ int ps[NBMAX];
    int t = threadIdx.x;
    int v = (t < nb) ? bucketCnt[t] : 0;
    ps[t] = v;
    __syncthreads();
#pragma unroll
    for (int off = 1; off < NBMAX; off <<= 1) {
        int u = 0;
        if (t >= off) u = ps[t - off];
        __syncthreads();
        ps[t] += u;
        __syncthreads();
    }
    if (t < nb) {
        int b = ps[t] - v; // exclusive
        bucketBase[t] = b;
        bucketCursor[t] = b;
    }
    if (t == 0) { bucketBase[nb] = E; rowptr[N] = E; }
}

__global__ __launch_bounds__(256) void bscatter_kernel(const int* __restrict__ src,
                                                       const int* __restrict__ dst,
                                                       int* __restrict__ bucketCursor,
                                                       uint2* __restrict__ pairs,
                                                       int E, int nb, int chunk) {
    __shared__ int cnt[NBMAX];
    __shared__ int base[NBMAX];
    int t = threadIdx.x;
    for (int i = t; i < nb; i += 256) cnt[i] = 0;
    __syncthreads();
    int s = blockIdx.x * chunk, e = s + chunk; if (e > E) e = E;
    for (int i = s + t; i < e; i += 256) atomicAdd(&cnt[dst[i] >> CSR_SHIFT], 1);
    __syncthreads();
    for (int i = t; i < nb; i += 256) {
        int c = cnt[i];
        base[i] = c ? atomicAdd(&bucketCursor[i], c) : 0;
    }
    __syncthreads();
    for (int i = t; i < nb; i += 256) cnt[i] = 0;
    __syncthreads();
    for (int i = s + t; i < e; i += 256) {
        int d = dst[i];
        int b = d >> CSR_SHIFT;
        int slot = atomicAdd(&cnt[b], 1);
        pairs[base[b] + slot] = make_uint2((unsigned)src[i], (unsigned)d);
    }
}

// colidx stores src*64 (precomputed ushort2-row offset for agg)
__global__ __launch_bounds__(256) void bbuild_kernel(const uint2* __restrict__ pairs,
                                                     const int* __restrict__ bucketBase,
                                                     int* __restrict__ rowptr,
                                                     int* __restrict__ colidx, int N) {
    __shared__ int cnt[128];
    int b = blockIdx.x, t = threadIdx.x;
    int lo = bucketBase[b], hi = bucketBase[b + 1];
    if (t < 128) cnt[t] = 0;
    __syncthreads();
    for (int e = lo + t; e < hi; e += 256) atomicAdd(&cnt[pairs[e].y & 127], 1);
    __syncthreads();
    int orig = (t < 128) ? cnt[t] : 0;
#pragma unroll
    for (int o = 1; o < 128; o <<= 1) {
        int u = 0;
        if (t < 128 && t >= o) u = cnt[t - o];
        __syncthreads();
        if (t < 128) cnt[t] += u;
        __syncthreads();
    }
    int ex = (t < 128) ? (cnt[t] - orig) : 0;
    if (t < 128) {
        int node = b * 128 + t;
        if (node < N) rowptr[node] = lo + ex;
    }
    __syncthreads();
    if (t < 128) cnt[t] = ex; // reuse as cursor
    __syncthreads();
    for (int e = lo + t; e < hi; e += 256) {
        uint2 p = pairs[e];
        int slot = atomicAdd(&cnt[p.y & 127], 1);
        colidx[lo + slot] = (int)p.x * 64;
    }
}

// coeff from striped stats [8][256]: a = g*rsqrt(var+eps), c = b - mean*a
__device__ inline void coeff_from_stats(const float* __restrict__ stats,
                                        const float* __restrict__ g,
                                        const float* __restrict__ bb,
                                        int col, int N, float& a, float& c) {
    float s = 0.f, q = 0.f;
#pragma unroll
    for (int st = 0; st < 8; ++st) {
        s += stats[st * 256 + col];
        q += stats[st * 256 + 128 + col];
    }
    float m = s / N, v = q / N - m * m;
    a = g[col] * rsqrtf(v + BN_EPS);
    c = bb[col] - m * a;
}

// folded bn2+bn3: f(u) = relu(a3*relu(a2u+c2)+c3) = max(A*u+C, D) (a2,a3>0)
__device__ inline void folded_coeffs(
    const float* __restrict__ stats2, const float* __restrict__ g2, const float* __restrict__ b2v,
    const float* __restrict__ stats3, const float* __restrict__ g3, const float* __restrict__ b3v,
    int col, int N, float& A, float& C, float& D) {
    float a2, c2, a3, c3;
    coeff_from_stats(stats2, g2, b2v, col, N, a2, c2);
    coeff_from_stats(stats3, g3, b3v, col, N, a3, c3);
    A = a3 * a2;
    C = fmaf(a3, c2, c3);
    D = fmaxf(c3, 0.f);
}

// ---------------- aggregation: rst[i] = f(x[i]) + sum_{j in in(i)} f(x[j]) ----------------
// X bf16. One wave per node (whole 256 B row per gather). colidx pre-scaled by 64.
// MODE 0: f = identity. MODE 1: f(u) = max(A*u+C, D), folded coeffs computed inline.

template <int MODE>
__global__ __launch_bounds__(256) void agg_kernel(
    const unsigned short* __restrict__ Xb, const int* __restrict__ rowptr,
    const int* __restrict__ colidx,
    const float* __restrict__ stats2, const float* __restrict__ g2, const float* __restrict__ b2v,
    const float* __restrict__ stats3, const float* __restrict__ g3, const float* __restrict__ b3v,
    float* __restrict__ rst, int N) {
    __shared__ float cf[3][128];
    int t = threadIdx.x;
    if (MODE) {
        if (t < 128) {
            float A, C, D;
            folded_coeffs(stats2, g2, b2v, stats3, g3, b3v, t, N, A, C, D);
            cf[0][t] = A; cf[1][t] = C; cf[2][t] = D;
        }
        __syncthreads();
    }
    int wv = __builtin_amdgcn_readfirstlane(t >> 6);
    int node = blockIdx.x * 4 + wv;
    if (node >= N) return;
    int lane = t & 63;
    int c0 = lane * 2, c1 = c0 + 1;
    float A0 = 1.f, C0 = 0.f, D0 = 0.f, A1 = 1.f, C1 = 0.f, D1 = 0.f;
    if (MODE) {
        A0 = cf[0][c0]; A1 = cf[0][c1];
        C0 = cf[1][c0]; C1 = cf[1][c1];
        D0 = cf[2][c0]; D1 = cf[2][c1];
    }
    auto fx = [&](float u) { return MODE ? fmaxf(fmaf(A0, u, C0), D0) : u; };
    auto fy = [&](float u) { return MODE ? fmaxf(fmaf(A1, u, C1), D1) : u; };
    const ushort2* X2 = (const ushort2*)Xb;
    ushort2 self = X2[node * 64 + lane];
    float ax = fx(bf2f((short)self.x)), ay = fy(bf2f((short)self.y));
    int e = rowptr[node], end = rowptr[node + 1];
    for (; e + 16 <= end; e += 16) {
        int j[16];
#pragma unroll
        for (int k = 0; k < 16; ++k) j[k] = colidx[e + k];
        ushort2 v[16];
#pragma unroll
        for (int k = 0; k < 16; ++k) v[k] = X2[j[k] + lane];
#pragma unroll
        for (int k = 0; k < 16; ++k) {
            ax += fx(bf2f((short)v[k].x));
            ay += fy(bf2f((short)v[k].y));
        }
    }
    for (; e + 4 <= end; e += 4) {
        int j[4];
#pragma unroll
        for (int k = 0; k < 4; ++k) j[k] = colidx[e + k];
        ushort2 v[4];
#pragma unroll
        for (int k = 0; k < 4; ++k) v[k] = X2[j[k] + lane];
#pragma unroll
        for (int k = 0; k < 4; ++k) {
            ax += fx(bf2f((short)v[k].x));
            ay += fy(bf2f((short)v[k].y));
        }
    }
    for (; e < end; ++e) {
        ushort2 v = X2[colidx[e] + lane];
        ax += fx(bf2f((short)v.x));
        ay += fy(bf2f((short)v.y));
    }
    float2 r; r.x = ax; r.y = ay;
    ((float2*)rst)[node * 64 + lane] = r;
}

// ---------------- GEMM: C = pre(A) @ W + bias, striped column stats ----------------
// W hi/lo staged in LDS (XOR-swizzled); A (f32) streamed global->registers.
// Split: hi = trunc16(x) (v_perm pack), lo = trunc16(x - hi).
// PRE==1: relu(a*x+c), coeffs per-lane from striped stats via __shfl.
// OUTBF==1: write C as bf16 (RNE), stats on rounded values.
// Epilogue order: bias->acc, stats reduce+atomics FIRST, global stores LAST
// (avoids vmcnt(0) store-drain at the stats __syncthreads).

template <int PRE, int OUTBF>
__global__ __launch_bounds__(256, 2) void gemm_kernel(
    const float* __restrict__ A,
    const short* __restrict__ WtHi, const short* __restrict__ WtLo,
    const float* __restrict__ bias,
    const float* __restrict__ preStats, const float* __restrict__ preG,
    const float* __restrict__ preB,
    float* __restrict__ C, unsigned short* __restrict__ Cb,
    float* __restrict__ outStats, int N) {
    __shared__ short WsHi[128 * 128];
    __shared__ short WsLo[128 * 128];

    const int t = threadIdx.x;
    const int row0 = blockIdx.x * 128;
    const int w = t >> 6, lane = t & 63;
    const int quad = lane >> 4, l16 = lane & 15;
    const int sw = (l16 & 7) * 8;

    float aE = 1.f, cE = 0.f, aO = 1.f, cO = 0.f;
    if (PRE) {
        coeff_from_stats(preStats, preG, preB, lane * 2, N, aE, cE);
        coeff_from_stats(preStats, preG, preB, lane * 2 + 1, N, aO, cO);
    }

    float4 af[2][4][2];
#pragma unroll
    for (int m = 0; m < 2; ++m) {
        int gr = row0 + w * 32 + m * 16 + l16;
        bool ok = gr < N;
        const float* Ar = A + (size_t)gr * 128;
#pragma unroll
        for (int kk = 0; kk < 4; ++kk) {
            int kb = kk * 32 + quad * 8;
            af[m][kk][0] = ok ? *(const float4*)(Ar + kb) : make_float4(0.f, 0.f, 0.f, 0.f);
            af[m][kk][1] = ok ? *(const float4*)(Ar + kb + 4) : make_float4(0.f, 0.f, 0.f, 0.f);
        }
    }

#pragma unroll
    for (int i = 0; i < 8; ++i) {
        int ch = t + i * 256;
        int r = ch >> 4, k = (ch & 15) * 8;
        int d = r * 128 + (k ^ ((r & 7) * 8));
        *(short8*)(WsHi + d) = *(const short8*)(WtHi + r * 128 + k);
        *(short8*)(WsLo + d) = *(const short8*)(WtLo + r * 128 + k);
    }
    __syncthreads();

    short8 fh[2][4], fl[2][4];
#pragma unroll
    for (int kk = 0; kk < 4; ++kk) {
        float a8[8], c8[8];
#pragma unroll
        for (int j = 0; j < 8; ++j) {
            if (PRE) {
                int col = kk * 32 + quad * 8 + j;
                int srcl = col >> 1;
                a8[j] = __shfl((j & 1) ? aO : aE, srcl, 64);
                c8[j] = __shfl((j & 1) ? cO : cE, srcl, 64);
            }
        }
#pragma unroll
        for (int m = 0; m < 2; ++m) {
            float x[8];
            *(float4*)(x) = af[m][kk][0];
            *(float4*)(x + 4) = af[m][kk][1];
            short8 h, lo;
#pragma unroll
            for (int j = 0; j < 4; ++j) {
                float x0 = x[2 * j], x1 = x[2 * j + 1];
                if (PRE) {
                    x0 = fmaxf(a8[2 * j] * x0 + c8[2 * j], 0.f);
                    x1 = fmaxf(a8[2 * j + 1] * x1 + c8[2 * j + 1], 0.f);
                }
                unsigned u0 = asu(x0), u1 = asu(x1);
                unsigned hp = __builtin_amdgcn_perm(u1, u0, 0x07060302u);
                float l0 = x0 - asf(u0 & 0xFFFF0000u);
                float l1 = x1 - asf(u1 & 0xFFFF0000u);
                unsigned lp = __builtin_amdgcn_perm(asu(l1), asu(l0), 0x07060302u);
                ((unsigned*)&h)[j] = hp;
                ((unsigned*)&lo)[j] = lp;
            }
            fh[m][kk] = h;
            fl[m][kk] = lo;
        }
    }

    f32x4 acc[2][8];
#pragma unroll
    for (int m = 0; m < 2; ++m)
#pragma unroll
        for (int n = 0; n < 8; ++n) acc[m][n] = (f32x4){0.f, 0.f, 0.f, 0.f};

#pragma unroll
    for (int kk = 0; kk < 4; ++kk) {
        int kb = kk * 32 + quad * 8;
        bf16x8 a0h = __builtin_bit_cast(bf16x8, fh[0][kk]);
        bf16x8 a1h = __builtin_bit_cast(bf16x8, fh[1][kk]);
        bf16x8 a0l = __builtin_bit_cast(bf16x8, fl[0][kk]);
        bf16x8 a1l = __builtin_bit_cast(bf16x8, fl[1][kk]);
#pragma unroll
        for (int n = 0; n < 8; ++n) {
            int woff = (n * 16 + l16) * 128 + (kb ^ sw);
            bf16x8 bh = __builtin_bit_cast(bf16x8, *(const short8*)(WsHi + woff));
            bf16x8 bl = __builtin_bit_cast(bf16x8, *(const short8*)(WsLo + woff));
            acc[0][n] = __builtin_amdgcn_mfma_f32_16x16x32_bf16(a0h, bh, acc[0][n], 0, 0, 0);
            acc[0][n] = __builtin_amdgcn_mfma_f32_16x16x32_bf16(a0l, bh, acc[0][n], 0, 0, 0);
            acc[0][n] = __builtin_amdgcn_mfma_f32_16x16x32_bf16(a0h, bl, acc[0][n], 0, 0, 0);
            acc[1][n] = __builtin_amdgcn_mfma_f32_16x16x32_bf16(a1h, bh, acc[1][n], 0, 0, 0);
            acc[1][n] = __builtin_amdgcn_mfma_f32_16x16x32_bf16(a1l, bh, acc[1][n], 0, 0, 0);
            acc[1][n] = __builtin_amdgcn_mfma_f32_16x16x32_bf16(a1h, bl, acc[1][n], 0, 0, 0);
        }
    }

    __syncthreads(); // LDS reads done; WsHi reused for stats reduction

    // bias into acc (+ bf16 round for OUTBF), stats partials from acc
    float bv[8];
#pragma unroll
    for (int n = 0; n < 8; ++n) bv[n] = bias[n * 16 + l16];
    float ls[8], lsq[8];
#pragma unroll
    for (int n = 0; n < 8; ++n) { ls[n] = 0.f; lsq[n] = 0.f; }
#pragma unroll
    for (int m = 0; m < 2; ++m) {
        int rbase = row0 + w * 32 + m * 16 + quad * 4;
#pragma unroll
        for (int n = 0; n < 8; ++n) {
#pragma unroll
            for (int r = 0; r < 4; ++r) {
                int row = rbase + r;
                if (row < N) {
                    float val = acc[m][n][r] + bv[n];
                    if (OUTBF) val = bf2f(f2bf(val));
                    acc[m][n][r] = val;
                    ls[n] += val;
                    lsq[n] += val * val;
                }
            }
        }
    }

    float* P = (float*)WsHi;
#pragma unroll
    for (int n = 0; n < 8; ++n) {
        float s = ls[n], q = lsq[n];
        s += __shfl_xor(s, 16, 64);
        s += __shfl_xor(s, 32, 64);
        q += __shfl_xor(q, 16, 64);
        q += __shfl_xor(q, 32, 64);
        if (quad == 0) {
            int colv = n * 16 + l16;
            P[w * 512 + colv] = s;
            P[w * 512 + 256 + colv] = q;
        }
    }
    __syncthreads();

    int stripe = blockIdx.x & 7;
    if (t < 128) {
        int col = t;
        float S = P[col] + P[512 + col] + P[1024 + col] + P[1536 + col];
        atomicAdd(&outStats[stripe * 256 + col], S);
    } else {
        int col = t - 128;
        float Q = P[256 + col] + P[768 + col] + P[1280 + col] + P[1792 + col];
        atomicAdd(&outStats[stripe * 256 + 128 + col], Q);
    }

    // global stores last (drain folds into kernel end)
#pragma unroll
    for (int m = 0; m < 2; ++m) {
        int rbase = row0 + w * 32 + m * 16 + quad * 4;
#pragma unroll
        for (int n = 0; n < 8; ++n) {
            int colv = n * 16 + l16;
#pragma unroll
            for (int r = 0; r < 4; ++r) {
                int row = rbase + r;
                if (row < N) {
                    if (OUTBF)
                        Cb[(size_t)row * 128 + colv] = (unsigned short)f2bf(acc[m][n][r]);
                    else
                        C[(size_t)row * 128 + colv] = acc[m][n][r];
                }
            }
        }
    }
}

// ---------------- stats of y = relu(a*x+c) over bf16 X (no materialization) ----------------

__global__ __launch_bounds__(256) void elt_kernel(
    const unsigned short* __restrict__ Xb,
    const float* __restrict__ inStats, const float* __restrict__ g, const float* __restrict__ bb,
    float* __restrict__ outStats, int N) {
    __shared__ float red[256 * 8];
    __shared__ float cf[2][128];
    int t = threadIdx.x;
    if (t < 128) {
        float a, c;
        coeff_from_stats(inStats, g, bb, t, N, a, c);
        cf[0][t] = a; cf[1][t] = c;
    }
    __syncthreads();
    int cg = t & 31;
    float a[4], c[4];
#pragma unroll
    for (int k = 0; k < 4; ++k) {
        a[k] = cf[0][cg * 4 + k];
        c[k] = cf[1][cg * 4 + k];
    }
    float sum[4] = {0.f, 0.f, 0.f, 0.f}, sq[4] = {0.f, 0.f, 0.f, 0.f};
    int total = N * 32;
    for (int i = blockIdx.x * 256 + t; i < total; i += gridDim.x * 256) {
        ushort4 u = ((const ushort4*)Xb)[i];
        float y0 = fmaxf(a[0] * bf2f((short)u.x) + c[0], 0.f);
        float y1 = fmaxf(a[1] * bf2f((short)u.y) + c[1], 0.f);
        float y2 = fmaxf(a[2] * bf2f((short)u.z) + c[2], 0.f);
        float y3 = fmaxf(a[3] * bf2f((short)u.w) + c[3], 0.f);
        sum[0] += y0; sq[0] += y0 * y0;
        sum[1] += y1; sq[1] += y1 * y1;
        sum[2] += y2; sq[2] += y2 * y2;
        sum[3] += y3; sq[3] += y3 * y3;
    }
#pragma unroll
    for (int k = 0; k < 4; ++k) { red[t * 8 + k] = sum[k]; red[t * 8 + 4 + k] = sq[k]; }
    __syncthreads();
    if (t < 32) {
        float S[4] = {0.f, 0.f, 0.f, 0.f}, Q[4] = {0.f, 0.f, 0.f, 0.f};
        for (int j = 0; j < 8; ++j) {
            int tt = t + 32 * j;
#pragma unroll
            for (int k = 0; k < 4; ++k) { S[k] += red[tt * 8 + k]; Q[k] += red[tt * 8 + 4 + k]; }
        }
        int stripe = blockIdx.x & 7;
#pragma unroll
        for (int k = 0; k < 4; ++k) {
            atomicAdd(&outStats[stripe * 256 + t * 4 + k], S[k]);
            atomicAdd(&outStats[stripe * 256 + 128 + t * 4 + k], Q[k]);
        }
    }
}

// ---------------- final: out = max(A*x+C, D) from bf16 X, coeffs inline ----------------

__global__ __launch_bounds__(256) void final_kernel(
    const unsigned short* __restrict__ Xb,
    const float* __restrict__ stats2, const float* __restrict__ g2, const float* __restrict__ b2v,
    const float* __restrict__ stats3, const float* __restrict__ g3, const float* __restrict__ b3v,
    float* __restrict__ out, int N) {
    __shared__ float cf[3][128];
    int t = threadIdx.x;
    if (t < 128) {
        float A, C, D;
        folded_coeffs(stats2, g2, b2v, stats3, g3, b3v, t, N, A, C, D);
        cf[0][t] = A; cf[1][t] = C; cf[2][t] = D;
    }
    __syncthreads();
    int cg = t & 31;
    float A[4], C[4], D[4];
#pragma unroll
    for (int k = 0; k < 4; ++k) {
        int colv = cg * 4 + k;
        A[k] = cf[0][colv];
        C[k] = cf[1][colv];
        D[k] = cf[2][colv];
    }
    int total = N * 32;
    for (int i = blockIdx.x * 256 + t; i < total; i += gridDim.x * 256) {
        ushort4 u = ((const ushort4*)Xb)[i];
        float4 y;
        y.x = fmaxf(fmaf(A[0], bf2f((short)u.x), C[0]), D[0]);
        y.y = fmaxf(fmaf(A[1], bf2f((short)u.y), C[1]), D[1]);
        y.z = fmaxf(fmaf(A[2], bf2f((short)u.z), C[2]), D[2]);
        y.w = fmaxf(fmaf(A[3], bf2f((short)u.w), C[3]), D[3]);
        ((float4*)out)[i] = y;
    }
}

// ---------------- launch ----------------

extern "C" void kernel_launch(void* const* d_in, const int* in_sizes, int n_in,
                              void* d_out, int out_size, void* d_ws, size_t ws_size,
                              hipStream_t stream) {
    const float* h0   = (const float*)d_in[0];
    const int*   src  = (const int*)d_in[1];
    const int*   dst  = (const int*)d_in[2];
    const float* W1   = (const float*)d_in[3];
    const float* b1   = (const float*)d_in[4];
    const float* W2   = (const float*)d_in[5];
    const float* b2   = (const float*)d_in[6];
    const float* bn1g = (const float*)d_in[7];
    const float* bn1b = (const float*)d_in[8];
    const float* bn2g = (const float*)d_in[9];
    const float* bn2b = (const float*)d_in[10];
    const float* bn3g = (const float*)d_in[11];
    const float* bn3b = (const float*)d_in[12];
    const int N = in_sizes[0] / 128;
    const int E = in_sizes[1];
    const int nb = (N + 127) >> CSR_SHIFT;

    char* ws = (char*)d_ws;
    size_t off = 0;
    auto alloc = [&](size_t bytes) {
        void* p = ws + off;
        off = (off + bytes + 255) & ~(size_t)255;
        return p;
    };
    float* stats        = (float*)alloc((size_t)5 * 3 * 8 * 256 * sizeof(float)); // striped
    int*   bucketCnt    = (int*)alloc((size_t)NBMAX * 4);
    int*   bucketBase   = (int*)alloc((size_t)(NBMAX + 1) * 4);
    int*   bucketCursor = (int*)alloc((size_t)NBMAX * 4);
    int*   rowptr       = (int*)alloc((size_t)(N + 1) * 4);
    int*   colidx       = (int*)alloc((size_t)E * 4);
    uint2* pairs        = (uint2*)alloc((size_t)E * 8);
    short* WtHi         = (short*)alloc((size_t)10 * 16384 * 2);
    short* WtLo         = (short*)alloc((size_t)10 * 16384 * 2);
    float* buf0         = (float*)alloc((size_t)N * 128 * 4);          // rst (f32)
    float* buf1         = (float*)alloc((size_t)N * 128 * 4);          // x1 (f32)
    unsigned short* xbf = (unsigned short*)alloc((size_t)N * 128 * 2); // h0/x2 (bf16)

    auto statsBase = [&](int l, int which) { return stats + ((size_t)(l * 3 + which)) * 8 * 256; };

    const int nstats = 5 * 3 * 8 * 256;
    int total4 = N * 32;
    setup_kernel<<<(total4 + 255) / 256, 256, 0, stream>>>(
        h0, xbf, total4, W1, W2, WtHi, WtLo, stats, nstats, bucketCnt, nb);

    const int chunk = 4096;
    const int chunkGrid = (E + chunk - 1) / chunk;
    bcount_kernel<<<chunkGrid, 256, 0, stream>>>(dst, bucketCnt, E, nb, chunk);
    bscan_kernel<<<1, 512, 0, stream>>>(bucketCnt, bucketBase, bucketCursor, rowptr, nb, N, E);
    bscatter_kernel<<<chunkGrid, 256, 0, stream>>>(src, dst, bucketCursor, pairs, E, nb, chunk);
    bbuild_kernel<<<nb, 256, 0, stream>>>(pairs, bucketBase, rowptr, colidx, N);

    const int gemmGrid = (N + 127) / 128;
    const int aggGrid = (N + 3) / 4;
    for (int l = 0; l < 5; ++l) {
        if (l == 0) {
            agg_kernel<0><<<aggGrid, 256, 0, stream>>>(
                xbf, rowptr, colidx,
                nullptr, nullptr, nullptr, nullptr, nullptr, nullptr,
                buf0, N);
        } else {
            int lp = l - 1;
            agg_kernel<1><<<aggGrid, 256, 0, stream>>>(
                xbf, rowptr, colidx,
                statsBase(lp, 1), bn2g + lp * 128, bn2b + lp * 128,
                statsBase(lp, 2), bn3g + lp * 128, bn3b + lp * 128,
                buf0, N);
        }
        gemm_kernel<0, 0><<<gemmGrid, 256, 0, stream>>>(
            buf0, WtHi + l * 16384, WtLo + l * 16384, b1 + l * 128,
            nullptr, nullptr, nullptr,
            buf1, nullptr, statsBase(l, 0), N);
        gemm_kernel<1, 1><<<gemmGrid, 256, 0, stream>>>(
            buf1, WtHi + (5 + l) * 16384, WtLo + (5 + l) * 16384, b2 + l * 128,
            statsBase(l, 0), bn1g + l * 128, bn1b + l * 128,
            nullptr, xbf, statsBase(l, 1), N);
        elt_kernel<<<256, 256, 0, stream>>>(
            xbf, statsBase(l, 1), bn2g + l * 128, bn2b + l * 128,
            statsBase(l, 2), N);
    }
    final_kernel<<<512, 256, 0, stream>>>(
        xbf,
        statsBase(4, 1), bn2g + 4 * 128, bn2b + 4 * 128,
        statsBase(4, 2), bn3g + 4 * 128, bn3b + 4 * 128,
        (float*)d_out, N);
}